// Round 11
// baseline (96.338 us; speedup 1.0000x reference)
//
#include <hip/hip_runtime.h>
#include <hip/hip_bf16.h>

typedef float f4 __attribute__((ext_vector_type(4)));
typedef short bf16x8 __attribute__((ext_vector_type(8)));

#define D 2048
#define RANK 16
#define NTHR 256      // 4 waves
#define TROWS 8       // rows per block (dup'd into 16-row MFMA)

__device__ __forceinline__ short bf16_of(float x) {
    return __builtin_bit_cast(short, __float2bfloat16(x));
}

__device__ __forceinline__ bf16x8 cvt8(f4 lo, f4 hi) {
    bf16x8 r;
    r[0] = bf16_of(lo.x); r[1] = bf16_of(lo.y);
    r[2] = bf16_of(lo.z); r[3] = bf16_of(lo.w);
    r[4] = bf16_of(hi.x); r[5] = bf16_of(hi.y);
    r[6] = bf16_of(hi.z); r[7] = bf16_of(hi.w);
    return r;
}

__device__ __forceinline__ float dot4(f4 a, f4 b) {
    return a.x * b.x + a.y * b.y + a.z * b.z + a.w * b.w;
}

// LDS-drain-only barrier: global loads/stores stay in flight across it.
__device__ __forceinline__ void barrier_lgkm() {
    asm volatile("s_waitcnt lgkmcnt(0)" ::: "memory");
    __builtin_amdgcn_s_barrier();
}

// out = h @ (A@B)^T via rank-16, "k1-shaped" fused kernel:
// 2048 small blocks (256 thr, 4 waves), one 8-row tile each.
//  - phase1 = R8-k1 body verbatim (proven 4.7 TB/s): per wave, K=512 slice,
//    16 MFMA steps, B and h BOTH streamed from memory (nothing register-
//    resident to fight the allocator for). Rows dup'd across m16 8-15
//    (same cache lines, free).
//  - 2 lgkm-only barriers for the 4-wave merge (tiny).
//  - phase2: A-slice fp32 in 64 VGPR (seg0 issued at kernel top -> in
//    flight during phase1), 2 e-segments x 8 rows, NT f4 stores where a
//    wave covers 1KB contiguous.
// Small blocks + ~3 blocks/CU + 2.7 generations => completion-staggered
// blocks keep reads and writes overlapped chip-wide (R5's missing property).
__global__ __launch_bounds__(NTHR, 3)
void lora_stream(const float* __restrict__ h, const float* __restrict__ A,
                 const float* __restrict__ B, float* __restrict__ out) {
    const int tid  = threadIdx.x;
    const int w    = tid >> 6;
    const int lane = tid & 63;
    const int m16  = lane & 15;
    const int kg   = lane >> 4;
    const int row  = m16 & 7;
    const long row0 = (long)blockIdx.x * TROWS;

    __shared__ f4 ldsT[4][16][4];    // per-wave T partials
    __shared__ f4 tt[TROWS][4];      // merged t[row][rank-quad]

    // ---- A seg0 (e = tid*4..+3), issued first, consumed in phase2 ----
    f4 Af[4][4];
#pragma unroll
    for (int j = 0; j < 4; ++j)
#pragma unroll
        for (int q = 0; q < 4; ++q)
            Af[j][q] = *(const f4*)(A + (long)(tid * 4 + j) * RANK + q * 4);

    // ---- phase1: wave w streams its K-slice [w*512, +512) ----
    const float* pB = B + (long)m16 * D + w * 512 + kg * 8;
    const float* pH = h + (row0 + row) * D + w * 512 + kg * 8;

    f4 a0 = {0.f, 0.f, 0.f, 0.f}, a1 = {0.f, 0.f, 0.f, 0.f};
#pragma unroll
    for (int s = 0; s < 8; ++s) {
        f4 bl = *(const f4*)(pB + s * 32);
        f4 bh = *(const f4*)(pB + s * 32 + 4);
        f4 hl = *(const f4*)(pH + s * 32);
        f4 hh = *(const f4*)(pH + s * 32 + 4);
        a0 = __builtin_amdgcn_mfma_f32_16x16x32_bf16(
            cvt8(bl, bh), cvt8(hl, hh), a0, 0, 0, 0);
    }
#pragma unroll
    for (int s = 8; s < 16; ++s) {
        f4 bl = *(const f4*)(pB + s * 32);
        f4 bh = *(const f4*)(pB + s * 32 + 4);
        f4 hl = *(const f4*)(pH + s * 32);
        f4 hh = *(const f4*)(pH + s * 32 + 4);
        a1 = __builtin_amdgcn_mfma_f32_16x16x32_bf16(
            cvt8(bl, bh), cvt8(hl, hh), a1, 0, 0, 0);
    }
    ldsT[w][m16][kg] = a0 + a1;

    barrier_lgkm();                      // ldsT ready
    if (tid < 32) {
        const int r = tid >> 2, q = tid & 3;
        tt[r][q] = ldsT[0][r][q] + ldsT[1][r][q] + ldsT[2][r][q] +
                   ldsT[3][r][q];
    }
    barrier_lgkm();                      // tt ready

    // ---- phase2: two e-segments x 8 rows, coalesced NT stores ----
#pragma unroll
    for (int si = 0; si < 2; ++si) {
        if (si == 1) {
            // reload A for segment 1 (L2-hot; latency hidden by seg0 tail)
#pragma unroll
            for (int j = 0; j < 4; ++j)
#pragma unroll
                for (int q = 0; q < 4; ++q)
                    Af[j][q] = *(const f4*)(
                        A + (long)(1024 + tid * 4 + j) * RANK + q * 4);
        }
        float* po = out + row0 * D + si * 1024 + tid * 4;
#pragma unroll
        for (int r = 0; r < TROWS; ++r) {
            const f4 t0 = tt[r][0], t1 = tt[r][1];
            const f4 t2 = tt[r][2], t3 = tt[r][3];
            f4 res;
            res.x = dot4(t0, Af[0][0]) + dot4(t1, Af[0][1]) +
                    dot4(t2, Af[0][2]) + dot4(t3, Af[0][3]);
            res.y = dot4(t0, Af[1][0]) + dot4(t1, Af[1][1]) +
                    dot4(t2, Af[1][2]) + dot4(t3, Af[1][3]);
            res.z = dot4(t0, Af[2][0]) + dot4(t1, Af[2][1]) +
                    dot4(t2, Af[2][2]) + dot4(t3, Af[2][3]);
            res.w = dot4(t0, Af[3][0]) + dot4(t1, Af[3][1]) +
                    dot4(t2, Af[3][2]) + dot4(t3, Af[3][3]);
            __builtin_nontemporal_store(res, (f4*)(po + (long)r * D));
        }
    }
}

extern "C" void kernel_launch(void* const* d_in, const int* in_sizes, int n_in,
                              void* d_out, int out_size, void* d_ws,
                              size_t ws_size, hipStream_t stream) {
    const float* h = (const float*)d_in[0];
    const float* A = (const float*)d_in[1];
    const float* B = (const float*)d_in[2];
    float* out = (float*)d_out;

    const int n_rows = in_sizes[0] / D;       // 16384
    const int blocks = n_rows / TROWS;        // 2048

    hipLaunchKernelGGL(lora_stream, dim3(blocks), dim3(NTHR), 0, stream,
                       h, A, B, out);
}